// Round 4
// baseline (544.025 us; speedup 1.0000x reference)
//
#include <hip/hip_runtime.h>
#include <math.h>

#define D_MODEL 1024
#define NUM_HEADS 16
#define D_HEAD 64
#define SEQ 2048
#define BATCH 2

typedef __attribute__((ext_vector_type(8))) short short8;
typedef __attribute__((ext_vector_type(4))) float float4v;

__device__ __forceinline__ short f2bf(float f) {
    unsigned u = __float_as_uint(f);
    u += 0x7FFFu + ((u >> 16) & 1u);
    return (short)(u >> 16);
}

// async global->LDS, 16B per lane. LDS dest must be uniform-base + lane*16.
#define GLOAD_LDS16(g, l)                                                     \
    __builtin_amdgcn_global_load_lds(                                         \
        (const __attribute__((address_space(1))) unsigned int*)(g),           \
        (__attribute__((address_space(3))) unsigned int*)(l), 16, 0, 0)

// ---------------------------------------------------------------------------
// Kernel 0: fp32 -> bf16 conversion for x and the four weight matrices.
// ---------------------------------------------------------------------------
__global__ __launch_bounds__(256) void cvt_bf16_kernel(
    const float* __restrict__ x,  const float* __restrict__ wq,
    const float* __restrict__ wk, const float* __restrict__ wv,
    const float* __restrict__ wo,
    short* __restrict__ xb,  short* __restrict__ wqb,
    short* __restrict__ wkb, short* __restrict__ wvb,
    short* __restrict__ wob)
{
    const int a = blockIdx.y;
    const float* src = (a == 0) ? x : (a == 1) ? wq : (a == 2) ? wk : (a == 3) ? wv : wo;
    short* dst = (a == 0) ? xb : (a == 1) ? wqb : (a == 2) ? wkb : (a == 3) ? wvb : wob;
    const int n = (a == 0) ? (BATCH * SEQ * D_MODEL) : (D_MODEL * D_MODEL);
    const int i = (blockIdx.x * 256 + threadIdx.x) * 8;
    if (i >= n) return;
    const float4 v0 = *(const float4*)(src + i);
    const float4 v1 = *(const float4*)(src + i + 4);
    short8 r;
    r[0] = f2bf(v0.x); r[1] = f2bf(v0.y); r[2] = f2bf(v0.z); r[3] = f2bf(v0.w);
    r[4] = f2bf(v1.x); r[5] = f2bf(v1.y); r[6] = f2bf(v1.z); r[7] = f2bf(v1.w);
    *(short8*)(dst + i) = r;
}

// ---------------------------------------------------------------------------
// m97-style bf16 MFMA GEMM core: y[m][n] = sum_k a[m][k] * b[n][k].
// 128x128 tile, BK=32, 256 threads (2x2 waves, each 64x64 via 4x4 MFMAs),
// global_load_lds width-16 staging, fp32 accumulate.
// ---------------------------------------------------------------------------
__device__ __forceinline__ void gemm_core_128(
    const short* __restrict__ a, const short* __restrict__ b,
    short* lA, short* lB, int m0, int n0, float4v acc[4][4])
{
    const int tid = threadIdx.x;
    const int lane = tid & 63;
    const int l15 = lane & 15, quad = lane >> 4;
    const int wave = tid >> 6;
    const int mw = (wave & 1) * 64, nw = (wave >> 1) * 64;
    const int srow = tid >> 2;            // 0..63
    const int scol = (tid & 3) * 8;       // 0,8,16,24

    const short* ag = a + (size_t)(m0 + srow) * D_MODEL + scol;
    const short* bg = b + (size_t)(n0 + srow) * D_MODEL + scol;
    short* lAd = lA + tid * 8;            // = wave-uniform base + lane*16B
    short* lBd = lB + tid * 8;

    for (int k0 = 0; k0 < D_MODEL; k0 += 32) {
        __syncthreads();                  // prior iter's ds_reads done
        GLOAD_LDS16(ag + k0, lAd);
        GLOAD_LDS16(ag + k0 + (size_t)64 * D_MODEL, lAd + 2048);
        GLOAD_LDS16(bg + k0, lBd);
        GLOAD_LDS16(bg + k0 + (size_t)64 * D_MODEL, lBd + 2048);
        __syncthreads();                  // vmcnt drained; tile visible

        short8 af[4], bf[4];
        #pragma unroll
        for (int i = 0; i < 4; i++)
            af[i] = *(const short8*)&lA[(mw + i * 16 + l15) * 32 + quad * 8];
        #pragma unroll
        for (int i = 0; i < 4; i++)
            bf[i] = *(const short8*)&lB[(nw + i * 16 + l15) * 32 + quad * 8];
        #pragma unroll
        for (int mi = 0; mi < 4; mi++)
            #pragma unroll
            for (int ni = 0; ni < 4; ni++)
                acc[mi][ni] = __builtin_amdgcn_mfma_f32_16x16x32_bf16(
                    af[mi], bf[ni], acc[mi][ni], 0, 0, 0);
    }
}

// ---------------------------------------------------------------------------
// Kernel 1: QKV projection (bf16 MFMA) + fused RoPE epilogue.
//   z=0: Q (B,H,S,D) bf16, scaled 1/8;  z=1: K (B,H,S,D);  z=2: Vt (B,H,D,S)
// Epilogue stages the output tile through LDS so ALL global stores are
// 16B/lane fully-coalesced (round-3 had 2B scattered stores -> 60x write
// amplification, 1.44 GB written, kernel purely write-bound).
// ---------------------------------------------------------------------------
__global__ __launch_bounds__(256) void qkv_mfma_kernel(
    const short* __restrict__ xb, const short* __restrict__ wqb,
    const short* __restrict__ wkb, const short* __restrict__ wvb,
    const int* __restrict__ pos,
    short* __restrict__ Qb, short* __restrict__ Kb, short* __restrict__ Vt)
{
    // one buffer: GEMM uses first 16KB as lA/lB; epilogue reuses all of it
    __shared__ __align__(16) short smem[128 * 136];   // 34816 B
    short* lA = smem;
    short* lB = smem + 4096;

    const int z = blockIdx.z;
    const short* w = (z == 0) ? wqb : (z == 1) ? wkb : wvb;
    const int m0 = blockIdx.y * 128, n0 = blockIdx.x * 128;

    float4v acc[4][4];
    #pragma unroll
    for (int i = 0; i < 4; i++)
        #pragma unroll
        for (int j = 0; j < 4; j++)
            acc[i][j] = (float4v){0.f, 0.f, 0.f, 0.f};

    gemm_core_128(xb, w, lA, lB, m0, n0, acc);

    const int tid = threadIdx.x;
    const int lane = tid & 63;
    const int l15 = lane & 15, quad = lane >> 4;
    const int wave = tid >> 6;
    const int mw = (wave & 1) * 64, nw = (wave >> 1) * 64;

    const int s_base = m0 & (SEQ - 1);
    const int bb = m0 >> 11;              // tile never crosses batch (128|2048)

    __syncthreads();                      // everyone done reading lA/lB

    if (z == 2) {
        // stage transposed [n][m], stride 136
        #pragma unroll
        for (int ni = 0; ni < 4; ni++) {
            #pragma unroll
            for (int mi = 0; mi < 4; mi++) {
                #pragma unroll
                for (int r = 0; r < 4; r++)
                    smem[(nw + ni * 16 + l15) * 136 + mw + mi * 16 + quad * 4 + r] =
                        f2bf(acc[mi][ni][r]);
            }
        }
        __syncthreads();
        // each (h,d) row: 128 s-values = 256B contiguous; 16 threads x 16B
        #pragma unroll
        for (int it = 0; it < 8; it++) {
            const int nloc = it * 16 + (tid >> 4);
            const int mloc = (tid & 15) * 8;
            const short8 val = *(const short8*)&smem[nloc * 136 + mloc];
            const int n = n0 + nloc;
            const int h = n >> 6, d = n & 63;
            *(short8*)(Vt + ((size_t)(bb * NUM_HEADS + h) * D_HEAD + d) * SEQ +
                       s_base + mloc) = val;
        }
    } else {
        short* dst = (z == 0) ? Qb : Kb;
        const float qs = (z == 0) ? 0.125f : 1.0f;
        // RoPE in registers (pair lives in adjacent lanes), stage [m][n]
        #pragma unroll
        for (int ni = 0; ni < 4; ni++) {
            const int n = n0 + nw + ni * 16 + l15;
            const int d = n & 63;
            const int fi = d >> 1;
            const float inv_freq = exp2f((float)fi * -0.4152410118609203f); // 10000^(-2fi/64)
            #pragma unroll
            for (int mi = 0; mi < 4; mi++) {
                #pragma unroll
                for (int r = 0; r < 4; r++) {
                    const int mloc = mw + mi * 16 + quad * 4 + r;
                    const float p = (float)pos[s_base + mloc];
                    float sn, cs;
                    sincosf(p * inv_freq, &sn, &cs);
                    const float val = acc[mi][ni][r];
                    const float partner = __shfl_xor(val, 1, 64);
                    const float res = (l15 & 1) ? fmaf(partner, sn, val * cs)
                                                : fmaf(val, cs, -partner * sn);
                    smem[mloc * 136 + nw + ni * 16 + l15] = f2bf(res * qs);
                }
            }
        }
        __syncthreads();
        // each (s, head) row: 64 d = 128B contiguous; 8 threads x 16B
        #pragma unroll
        for (int it = 0; it < 8; it++) {
            const int ri = it * 32 + (tid >> 3);   // 0..255 = m(128) x half(2)
            const int mloc = ri & 127;
            const int hh = ri >> 7;
            const int nloc = hh * 64 + (tid & 7) * 8;
            const short8 val = *(const short8*)&smem[mloc * 136 + nloc];
            const int n = n0 + nloc;
            const int h = n >> 6, d = n & 63;
            *(short8*)(dst + ((size_t)(bb * NUM_HEADS + h) * SEQ + s_base + mloc) *
                       D_HEAD + d) = val;
        }
    }
}

// ---------------------------------------------------------------------------
// Kernel 2: causal flash attention via mfma_f32_16x16x32_bf16 (validated);
// emits bf16 A for the MFMA out-projection.
// ---------------------------------------------------------------------------
__global__ __launch_bounds__(256) void attn_mfma_kernel(
    const short* __restrict__ Qb, const short* __restrict__ Kb,
    const short* __restrict__ Vt, short* __restrict__ Ab)
{
    __shared__ __align__(16) short lK[32 * 72];
    __shared__ __align__(16) short lV[64 * 56];
    __shared__ __align__(16) short lP[4][16 * 56];

    const int tid = threadIdx.x;
    const int lane = tid & 63;
    const int wave = tid >> 6;
    const int l15 = lane & 15;
    const int quad = lane >> 4;

    const int bh = blockIdx.x & (BATCH * NUM_HEADS - 1);
    const int qt = (SEQ / 64 - 1) - (blockIdx.x >> 5);
    const int q0w = qt * 64 + wave * 16;

    const short* Kg = Kb + (size_t)bh * SEQ * D_HEAD;
    const short* Vg = Vt + (size_t)bh * D_HEAD * SEQ;

    const short* Qrow = Qb + ((size_t)bh * SEQ + q0w + l15) * D_HEAD;
    const short8 qf0 = *(const short8*)(Qrow + quad * 8);
    const short8 qf1 = *(const short8*)(Qrow + 32 + quad * 8);

    float4v o0 = {0.f, 0.f, 0.f, 0.f}, o1 = o0, o2 = o0, o3 = o0;
    float lp[4] = {0.f, 0.f, 0.f, 0.f};

    const int nt = qt * 2 + 2;
    const int krow = tid & 31, kch = tid >> 5;
    const int vrow = tid >> 2, vch = tid & 3;

    short8 kreg = *(const short8*)(Kg + (size_t)krow * D_HEAD + kch * 8);
    short8 vreg = *(const short8*)(Vg + (size_t)vrow * SEQ + vch * 8);

    for (int t = 0; t < nt; t++) {
        const int kt0 = t * 32;
        __syncthreads();
        *(short8*)&lK[krow * 72 + kch * 8] = kreg;
        *(short8*)&lV[vrow * 56 + vch * 8] = vreg;
        __syncthreads();
        if (t + 1 < nt) {
            kreg = *(const short8*)(Kg + (size_t)(kt0 + 32 + krow) * D_HEAD + kch * 8);
            vreg = *(const short8*)(Vg + (size_t)vrow * SEQ + kt0 + 32 + vch * 8);
        }
        if (kt0 > q0w + 15) continue;

        float4v s0 = {0.f, 0.f, 0.f, 0.f}, s1 = {0.f, 0.f, 0.f, 0.f};
        {
            const short8 b00 = *(const short8*)&lK[l15 * 72 + quad * 8];
            const short8 b10 = *(const short8*)&lK[(16 + l15) * 72 + quad * 8];
            s0 = __builtin_amdgcn_mfma_f32_16x16x32_bf16(qf0, b00, s0, 0, 0, 0);
            s1 = __builtin_amdgcn_mfma_f32_16x16x32_bf16(qf0, b10, s1, 0, 0, 0);
            const short8 b01 = *(const short8*)&lK[l15 * 72 + 32 + quad * 8];
            const short8 b11 = *(const short8*)&lK[(16 + l15) * 72 + 32 + quad * 8];
            s0 = __builtin_amdgcn_mfma_f32_16x16x32_bf16(qf1, b01, s0, 0, 0, 0);
            s1 = __builtin_amdgcn_mfma_f32_16x16x32_bf16(qf1, b11, s1, 0, 0, 0);
        }

        if (kt0 + 31 > q0w) {
            const int qbase = q0w + quad * 4;
            #pragma unroll
            for (int r = 0; r < 4; r++) {
                if (kt0 + l15 > qbase + r)      s0[r] = -INFINITY;
                if (kt0 + 16 + l15 > qbase + r) s1[r] = -INFINITY;
            }
        }

        float p0[4], p1[4];
        #pragma unroll
        for (int r = 0; r < 4; r++) {
            p0[r] = __expf(s0[r]);
            p1[r] = __expf(s1[r]);
            lp[r] += p0[r] + p1[r];
        }

        short* Pw = lP[wave];
        #pragma unroll
        for (int r = 0; r < 4; r++) {
            Pw[(quad * 4 + r) * 56 + l15]      = f2bf(p0[r]);
            Pw[(quad * 4 + r) * 56 + 16 + l15] = f2bf(p1[r]);
        }
        const short8 pa = *(const short8*)&lP[wave][l15 * 56 + quad * 8];

        const short8 v0 = *(const short8*)&lV[(0 * 16 + l15) * 56 + quad * 8];
        const short8 v1 = *(const short8*)&lV[(1 * 16 + l15) * 56 + quad * 8];
        const short8 v2 = *(const short8*)&lV[(2 * 16 + l15) * 56 + quad * 8];
        const short8 v3 = *(const short8*)&lV[(3 * 16 + l15) * 56 + quad * 8];
        o0 = __builtin_amdgcn_mfma_f32_16x16x32_bf16(pa, v0, o0, 0, 0, 0);
        o1 = __builtin_amdgcn_mfma_f32_16x16x32_bf16(pa, v1, o1, 0, 0, 0);
        o2 = __builtin_amdgcn_mfma_f32_16x16x32_bf16(pa, v2, o2, 0, 0, 0);
        o3 = __builtin_amdgcn_mfma_f32_16x16x32_bf16(pa, v3, o3, 0, 0, 0);
    }

    #pragma unroll
    for (int off = 1; off <= 8; off <<= 1) {
        #pragma unroll
        for (int r = 0; r < 4; r++) lp[r] += __shfl_xor(lp[r], off, 64);
    }

    const int b = bh >> 4, h = bh & 15;
    short* Ap = Ab + ((size_t)(b * SEQ) + q0w + quad * 4) * D_MODEL + h * D_HEAD;
    #pragma unroll
    for (int r = 0; r < 4; r++) {
        const float inv = 1.0f / lp[r];
        Ap[(size_t)r * D_MODEL + l15]      = f2bf(o0[r] * inv);
        Ap[(size_t)r * D_MODEL + 16 + l15] = f2bf(o1[r] * inv);
        Ap[(size_t)r * D_MODEL + 32 + l15] = f2bf(o2[r] * inv);
        Ap[(size_t)r * D_MODEL + 48 + l15] = f2bf(o3[r] * inv);
    }
}

// ---------------------------------------------------------------------------
// Kernel 3: output projection (bf16 MFMA), fp32 out. Stores are 64B-contiguous
// per quad (fp32 x 16 lanes) -> no significant amplification.
// ---------------------------------------------------------------------------
__global__ __launch_bounds__(256) void out_mfma_kernel(
    const short* __restrict__ Ab, const short* __restrict__ wob,
    float* __restrict__ out)
{
    __shared__ __align__(16) short lA[128 * 32];
    __shared__ __align__(16) short lB[128 * 32];

    const int m0 = blockIdx.y * 128, n0 = blockIdx.x * 128;

    float4v acc[4][4];
    #pragma unroll
    for (int i = 0; i < 4; i++)
        #pragma unroll
        for (int j = 0; j < 4; j++)
            acc[i][j] = (float4v){0.f, 0.f, 0.f, 0.f};

    gemm_core_128(Ab, wob, lA, lB, m0, n0, acc);

    const int tid = threadIdx.x;
    const int lane = tid & 63;
    const int l15 = lane & 15, quad = lane >> 4;
    const int wave = tid >> 6;
    const int mw = (wave & 1) * 64, nw = (wave >> 1) * 64;

    #pragma unroll
    for (int mi = 0; mi < 4; mi++) {
        #pragma unroll
        for (int r = 0; r < 4; r++) {
            const int m = m0 + mw + mi * 16 + quad * 4 + r;
            float* op = out + (size_t)m * D_MODEL + n0 + nw + l15;
            #pragma unroll
            for (int ni = 0; ni < 4; ni++)
                op[ni * 16] = acc[mi][ni][r];
        }
    }
}

// ---------------------------------------------------------------------------
extern "C" void kernel_launch(void* const* d_in, const int* in_sizes, int n_in,
                              void* d_out, int out_size, void* d_ws, size_t ws_size,
                              hipStream_t stream)
{
    const float* x  = (const float*)d_in[0];
    const int*  pos = (const int*)d_in[1];
    const float* wq = (const float*)d_in[2];
    const float* wk = (const float*)d_in[3];
    const float* wv = (const float*)d_in[4];
    const float* wo = (const float*)d_in[5];
    float* out = (float*)d_out;

    const size_t nx = (size_t)BATCH * SEQ * D_MODEL;   // 4M
    const size_t nw = (size_t)D_MODEL * D_MODEL;       // 1M
    short* xb  = (short*)d_ws;
    short* wqb = xb + nx;
    short* wkb = wqb + nw;
    short* wvb = wkb + nw;
    short* wob = wvb + nw;
    short* Qb  = wob + nw;
    short* Kb  = Qb + nx;
    short* Vt  = Kb + nx;
    short* Ab  = Vt + nx;

    dim3 blk(256);
    cvt_bf16_kernel<<<dim3(2048, 5), blk, 0, stream>>>(x, wq, wk, wv, wo,
                                                       xb, wqb, wkb, wvb, wob);
    qkv_mfma_kernel<<<dim3(8, 32, 3), blk, 0, stream>>>(xb, wqb, wkb, wvb, pos,
                                                        Qb, Kb, Vt);
    attn_mfma_kernel<<<dim3(BATCH * NUM_HEADS * (SEQ / 64)), blk, 0, stream>>>(Qb, Kb, Vt, Ab);
    out_mfma_kernel<<<dim3(8, 32), blk, 0, stream>>>(Ab, wob, out);
}